// Round 21
// baseline (46.839 us; speedup 1.0000x reference)
//
#include <hip/hip_runtime.h>
#include <hip/hip_fp16.h>
#include <math.h>

#define TT 8192
#define FF 64
#define TILE 32
#define HALO 50
#define ROWS 82              // TILE + HALO
#define XSTR 72              // f16 row stride for xsH

typedef float f32x2 __attribute__((ext_vector_type(2)));
typedef float f32x4 __attribute__((ext_vector_type(4)));
typedef _Float16 f16x8 __attribute__((ext_vector_type(8)));
typedef unsigned int u32x4 __attribute__((ext_vector_type(4)));
typedef unsigned int u32x2 __attribute__((ext_vector_type(2)));

__device__ __forceinline__ float rcpf(float x) { return __builtin_amdgcn_rcpf(x); }

// ---- prep: wsmH[j*64+i] = f16 softmax(W)[i][j]; pwB = f16 MFMA B-frags of PW;
//      cpad[57]: cpad[q] = coeffs[q-3] for 0<=q-3<=50 else 0
__global__ void prep_kernel(const float* __restrict__ W, const float* __restrict__ PW,
                            const float* __restrict__ C,
                            __half* __restrict__ wsmH, u32x4* __restrict__ pwB,
                            float* __restrict__ cpad) {
    const int lane = threadIdx.x;
    const int wv   = threadIdx.y;
    const int tid  = wv * 64 + lane;
    for (int it = 0; it < 16; ++it) {
        const int r = wv * 16 + it;
        float v = W[r * 64 + lane];
        float m = v;
        #pragma unroll
        for (int off = 32; off >= 1; off >>= 1)
            m = fmaxf(m, __shfl_xor(m, off, 64));
        float e = __expf(v - m);
        float s = e;
        #pragma unroll
        for (int off = 32; off >= 1; off >>= 1)
            s += __shfl_xor(s, off, 64);
        wsmH[lane * 64 + r] = __float2half(e * rcpf(s));   // [j][i]
    }
    for (int s = tid; s < 512; s += 256) {
        const int n2 = s >> 6;
        const int ln = s & 63;
        const int i  = (n2 >> 1) * 16 + (ln & 15);
        const int k0 = (n2 & 1) * 32 + (ln >> 4) * 8;
        u32x4 frag;
        #pragma unroll
        for (int w = 0; w < 4; ++w) {
            const unsigned lo = __half_as_ushort(__float2half_rn(PW[i * 64 + k0 + 2 * w]));
            const unsigned hi = __half_as_ushort(__float2half_rn(PW[i * 64 + k0 + 2 * w + 1]));
            frag[w] = lo | (hi << 16);
        }
        pwB[s] = frag;
    }
    if (tid < 57) {
        const int k = tid - 3;
        cpad[tid] = (k >= 0 && k <= 50) ? C[k] : 0.f;
    }
}

// ---- fused main: 512 thr / 8 waves, 32-row tile; FIR stream in registers ----
__global__ __launch_bounds__(512, 4)
void mcao_main(const float* __restrict__ x,
               const __half* __restrict__ wsmH,
               const u32x4* __restrict__ pwB,
               const float* __restrict__ cpad,
               const float* __restrict__ pb,
               const float* __restrict__ kap,
               float* __restrict__ out,
               float* __restrict__ memout) {
    // LDS 37408 B:
    //   [0, 11808)      xsH f16 [82][72]   (dead after MFMA reads)
    //   [0, 8448)       P2  f32 [64][33]   (overlays xsH after bar2)
    //   [11808, 29216)  tuS f32x2 [64][34] {t,u}[feat][row]
    //   [29216, 37408)  wT  f16 [64][64]   softmax(W) at [j*64+i]
    __shared__ __align__(16) char smem[37408];
    __half* xsH = (__half*)smem;
    float*  P2  = (float*)smem;
    f32x2*  tuS = (f32x2*)(smem + 11808);
    __half* wT  = (__half*)(smem + 29216);

    const int tid  = threadIdx.x;
    const int lane = tid & 63;
    const int wv   = tid >> 6;              // 0..7

    const int sw = ((int)blockIdx.x & 7) * 128 + ((int)blockIdx.x >> 3);
    const int b  = sw >> 8;
    const int t0 = (sw & 255) * TILE;
    const float* xb = x + (size_t)b * TT * FF;

    // ---- FIR stream -> 54 f32 registers (global, coalesced, L2-hot) ----
    // issued first: latency hides under the staging phase below
    const int firrow = 4 * wv;
    const int gbase  = t0 - HALO + firrow;
    float xfir[54];
    #pragma unroll
    for (int m = 0; m < 54; ++m) {
        const int t = gbase + m;
        xfir[m] = (t >= 0) ? xb[(size_t)t * 64 + lane] : 0.f;
    }

    // ---- stage xsH (f16) + t/u planes inline (f32 source) + wT ----
    for (int i4 = tid; i4 < ROWS * 16; i4 += 512) {
        const int s = i4 >> 4, f4 = i4 & 15, t = t0 - HALO + s;
        f32x4 v = {0.f, 0.f, 0.f, 0.f};
        if (t >= 0) v = *(const f32x4*)(xb + (size_t)t * 64 + f4 * 4);
        __half hv[4];
        #pragma unroll
        for (int q = 0; q < 4; ++q) hv[q] = __float2half_rn(v[q]);
        *(u32x2*)(&xsH[s * XSTR + f4 * 4]) = *(u32x2*)hv;
        if (s >= HALO) {
            const int row = s - HALO;
            #pragma unroll
            for (int q = 0; q < 4; ++q) {
                f32x2 e;
                e.x = fmaf(-2.f, rcpf(__expf(2.f * v[q]) + 1.f), 1.f);  // tanh
                e.y = __expf(-fabsf(v[q]));                             // e^-|x|
                tuS[(f4 * 4 + q) * 34 + row] = e;
            }
        }
    }
    ((f32x4*)wT)[tid] = ((const f32x4*)wsmH)[tid];
    __syncthreads();                                    // bar1

    // ---- proj via MFMA ----
    const int mt = wv >> 2, nt = wv & 3;
    const int marow = HALO + mt * 16 + (lane & 15);
    const int kcol  = (lane >> 4) * 8;
    f32x4 cfr = {0.f, 0.f, 0.f, 0.f};
    #pragma unroll
    for (int kt = 0; kt < 2; ++kt) {
        const f16x8 afr = *(const f16x8*)(&xsH[marow * XSTR + kt * 32 + kcol]);
        const f16x8 bfr = __builtin_bit_cast(f16x8, pwB[(nt * 2 + kt) * 64 + lane]);
        cfr = __builtin_amdgcn_mfma_f32_16x16x32_f16(afr, bfr, cfr, 0, 0, 0);
    }

    // ---- megaloop setup ----
    const int r  = lane & 31;
    const int h  = lane >> 5;
    const int ib = wv * 8 + h * 4;
    f32x2 tiP0, tiP1, uiP0, uiP1;
    {
        const f32x2 e0 = tuS[(ib + 0) * 34 + r];
        const f32x2 e1 = tuS[(ib + 1) * 34 + r];
        const f32x2 e2 = tuS[(ib + 2) * 34 + r];
        const f32x2 e3 = tuS[(ib + 3) * 34 + r];
        tiP0.x = e0.x; tiP0.y = e1.x; uiP0.x = e0.y; uiP0.y = e1.y;
        tiP1.x = e2.x; tiP1.y = e3.x; uiP1.x = e2.y; uiP1.y = e3.y;
    }

    float macc[4] = {0.f, 0.f, 0.f, 0.f};
    f32x2 cac0 = {0.f, 0.f}, cac1 = {0.f, 0.f};
    const f32x2 one2 = {1.f, 1.f};

    // ---- megaloop m = 0..53 (FIR from regs + coupling), FULL unroll ----
    #pragma unroll
    for (int m = 0; m < 54; ++m) {
        const f32x2 e = tuS[m * 34 + r];                     // b64, 2-way free
        __half wh[4];
        *(u32x2*)wh = *(const u32x2*)(&wT[m * 64 + ib]);     // 2-addr b64 broadcast
        #pragma unroll
        for (int r2 = 0; r2 < 4; ++r2)
            macc[r2] = fmaf(cpad[r2 + 53 - m], xfir[m], macc[r2]);  // SGPR x reg
        const f32x2 tjj = {e.x, e.x}, ujj = {e.y, e.y};
        {
            const f32x2 d1  = __builtin_elementwise_fma(-tiP0, tjj, one2);
            const f32x2 d2  = __builtin_elementwise_fma( uiP0, ujj, one2);
            const f32x2 den = d1 * d2;
            f32x2 rr; rr.x = rcpf(den.x); rr.y = rcpf(den.y);
            const f32x2 s = (tiP0 - tjj) * rr;
            cac0.x = fmaf(__half2float(wh[0]), s.x, cac0.x);
            cac0.y = fmaf(__half2float(wh[1]), s.y, cac0.y);
        }
        {
            const f32x2 d1  = __builtin_elementwise_fma(-tiP1, tjj, one2);
            const f32x2 d2  = __builtin_elementwise_fma( uiP1, ujj, one2);
            const f32x2 den = d1 * d2;
            f32x2 rr; rr.x = rcpf(den.x); rr.y = rcpf(den.y);
            const f32x2 s = (tiP1 - tjj) * rr;
            cac1.x = fmaf(__half2float(wh[2]), s.x, cac1.x);
            cac1.y = fmaf(__half2float(wh[3]), s.y, cac1.y);
        }
    }
    // ---- m = 54..63 (coupling only), FULL unroll ----
    #pragma unroll
    for (int m = 54; m < 64; ++m) {
        const f32x2 e = tuS[m * 34 + r];
        __half wh[4];
        *(u32x2*)wh = *(const u32x2*)(&wT[m * 64 + ib]);
        const f32x2 tjj = {e.x, e.x}, ujj = {e.y, e.y};
        {
            const f32x2 d1  = __builtin_elementwise_fma(-tiP0, tjj, one2);
            const f32x2 d2  = __builtin_elementwise_fma( uiP0, ujj, one2);
            const f32x2 den = d1 * d2;
            f32x2 rr; rr.x = rcpf(den.x); rr.y = rcpf(den.y);
            const f32x2 s = (tiP0 - tjj) * rr;
            cac0.x = fmaf(__half2float(wh[0]), s.x, cac0.x);
            cac0.y = fmaf(__half2float(wh[1]), s.y, cac0.y);
        }
        {
            const f32x2 d1  = __builtin_elementwise_fma(-tiP1, tjj, one2);
            const f32x2 d2  = __builtin_elementwise_fma( uiP1, ujj, one2);
            const f32x2 den = d1 * d2;
            f32x2 rr; rr.x = rcpf(den.x); rr.y = rcpf(den.y);
            const f32x2 s = (tiP1 - tjj) * rr;
            cac1.x = fmaf(__half2float(wh[2]), s.x, cac1.x);
            cac1.y = fmaf(__half2float(wh[3]), s.y, cac1.y);
        }
    }

    // ---- memory-term store ----
    #pragma unroll
    for (int r2 = 0; r2 < 4; ++r2)
        memout[(size_t)(b * TT + t0 + firrow + r2) * 64 + lane] = macc[r2];

    __syncthreads();                                    // bar2 (xsH dead)

    // ---- proj C-frag -> P2 ----
    {
        const int ic = nt * 16 + (lane & 15);
        const int rb = mt * 16 + (lane >> 4) * 4;
        #pragma unroll
        for (int reg = 0; reg < 4; ++reg)
            P2[ic * 33 + rb + reg] = cfr[reg];
    }
    __syncthreads();                                    // bar3

    // ---- epilogue RMW ----
    const float kappa = kap[0];
    const float ksum  = (1.f - __expf(-kappa * (float)(t0 + r + 1))) *
                        rcpf(1.f - __expf(-kappa));
    const f32x4 pbv = *(const f32x4*)(pb + ib);
    #pragma unroll
    for (int q = 0; q < 4; ++q) {
        const float cv = (q & 1) ? ((q >> 1) ? cac1.y : cac0.y)
                                 : ((q >> 1) ? cac1.x : cac0.x);
        const int idx = (ib + q) * 33 + r;
        P2[idx] = fmaf(0.4f, cv, 0.3f * (P2[idx] + pbv[q]) * ksum);
    }
    __syncthreads();                                    // bar4

    // ---- final store ----
    #pragma unroll
    for (int rr2 = 0; rr2 < 4; ++rr2) {
        const int row = 4 * wv + rr2;
        out[(size_t)(b * TT + t0 + row) * 64 + lane] =
            fmaf(0.3f, macc[rr2], P2[lane * 33 + row]);
    }
}

extern "C" void kernel_launch(void* const* d_in, const int* in_sizes, int n_in,
                              void* d_out, int out_size, void* d_ws, size_t ws_size,
                              hipStream_t stream) {
    const float* x   = (const float*)d_in[0];
    const float* W   = (const float*)d_in[1];
    const float* PW  = (const float*)d_in[2];
    const float* pb  = (const float*)d_in[3];
    const float* kap = (const float*)d_in[4];
    const float* cf  = (const float*)d_in[5];

    float* out    = (float*)d_out;
    float* memout = out + (size_t)4 * TT * FF;

    __half* wsmH = (__half*)d_ws;                        // 8 KB
    u32x4*  pwB  = (u32x4*)((char*)d_ws + 8192);         // 8 KB
    float*  cpad = (float*)((char*)d_ws + 16384);        // 228 B

    hipLaunchKernelGGL(prep_kernel, dim3(1), dim3(64, 4), 0, stream,
                       W, PW, cf, wsmH, pwB, cpad);
    hipLaunchKernelGGL(mcao_main, dim3(4 * (TT / TILE)), dim3(512), 0, stream,
                       x, wsmH, pwB, cpad, pb, kap, out, memout);
}

// Round 22
// 41.530 us; speedup vs baseline: 1.1278x; 1.1278x over previous
//
#include <hip/hip_runtime.h>
#include <hip/hip_fp16.h>
#include <math.h>

#define TT 8192
#define FF 64
#define TILE 64
#define HALO 50
#define ROWS 114             // TILE + HALO
#define XSTR 72              // f16 row stride for xsH

typedef float f32x2 __attribute__((ext_vector_type(2)));
typedef float f32x4 __attribute__((ext_vector_type(4)));
typedef _Float16 f16x8 __attribute__((ext_vector_type(8)));
typedef unsigned int u32x4 __attribute__((ext_vector_type(4)));
typedef unsigned int u32x2 __attribute__((ext_vector_type(2)));

__device__ __forceinline__ float rcpf(float x) { return __builtin_amdgcn_rcpf(x); }

// ---- prep: wsmT[j*64+i] = f32 softmax(W)[i][j]; pwB = f16 MFMA B-frags of PW;
//      cpad2[65]: cpad2[q] = coeffs[q-7] for 0<=q-7<=50 else 0
__global__ void prep_kernel(const float* __restrict__ W, const float* __restrict__ PW,
                            const float* __restrict__ C,
                            float* __restrict__ wsmT, u32x4* __restrict__ pwB,
                            float* __restrict__ cpad2) {
    const int lane = threadIdx.x;
    const int wv   = threadIdx.y;
    const int tid  = wv * 64 + lane;
    for (int it = 0; it < 16; ++it) {
        const int r = wv * 16 + it;
        float v = W[r * 64 + lane];
        float m = v;
        #pragma unroll
        for (int off = 32; off >= 1; off >>= 1)
            m = fmaxf(m, __shfl_xor(m, off, 64));
        float e = __expf(v - m);
        float s = e;
        #pragma unroll
        for (int off = 32; off >= 1; off >>= 1)
            s += __shfl_xor(s, off, 64);
        wsmT[lane * 64 + r] = e * rcpf(s);     // [j][i] f32
    }
    for (int s = tid; s < 512; s += 256) {
        const int n2 = s >> 6;
        const int ln = s & 63;
        const int i  = (n2 >> 1) * 16 + (ln & 15);
        const int k0 = (n2 & 1) * 32 + (ln >> 4) * 8;
        u32x4 frag;
        #pragma unroll
        for (int w = 0; w < 4; ++w) {
            const unsigned lo = __half_as_ushort(__float2half_rn(PW[i * 64 + k0 + 2 * w]));
            const unsigned hi = __half_as_ushort(__float2half_rn(PW[i * 64 + k0 + 2 * w + 1]));
            frag[w] = lo | (hi << 16);
        }
        pwB[s] = frag;
    }
    if (tid < 65) {
        const int k = tid - 7;
        cpad2[tid] = (k >= 0 && k <= 50) ? C[k] : 0.f;
    }
}

// ---- fused main: 512 thr / 8 waves, 64-row tile; lane = row, 8 feats/wave;
//      w via wave-uniform s_load (scalar pipe), NOT LDS ----
__global__ __launch_bounds__(512, 4)
void mcao_main(const float* __restrict__ x,
               const float* __restrict__ wsm,
               const u32x4* __restrict__ pwB,
               const float* __restrict__ cpad2,
               const float* __restrict__ pb,
               const float* __restrict__ kap,
               float* __restrict__ out,
               float* __restrict__ memout) {
    // LDS 49696 B -> 2 blocks/CU (grid 512 = exactly 2/CU):
    //   [0, 16416)      xsH f16 [114][72]    (FIR stream + MFMA-A)
    //   [16416, 49696)  tuS f32x2 [64][65]   {t,u}[feat][row]; P2 f32 [64][65] overlays after bar2
    __shared__ __align__(16) char smem[49696];
    __half* xsH = (__half*)smem;
    f32x2*  tuS = (f32x2*)(smem + 16416);
    float*  P2  = (float*)(smem + 16416);

    const int tid  = threadIdx.x;
    const int lane = tid & 63;
    const int wv   = tid >> 6;              // 0..7

    // XCD-aware bijective swizzle: 512 blocks -> 64 consecutive tiles per XCD
    const int sw = ((int)blockIdx.x & 7) * 64 + ((int)blockIdx.x >> 3);
    const int b  = sw >> 7;                 // 0..3
    const int t0 = (sw & 127) * TILE;
    const float* xb = x + (size_t)b * TT * FF;

    // ---- stage xsH (f16) + t/u planes inline (f32 source) ----
    for (int i4 = tid; i4 < ROWS * 16; i4 += 512) {
        const int s = i4 >> 4, f4 = i4 & 15, t = t0 - HALO + s;
        f32x4 v = {0.f, 0.f, 0.f, 0.f};
        if (t >= 0) v = *(const f32x4*)(xb + (size_t)t * 64 + f4 * 4);
        __half hv[4];
        #pragma unroll
        for (int q = 0; q < 4; ++q) hv[q] = __float2half_rn(v[q]);
        *(u32x2*)(&xsH[s * XSTR + f4 * 4]) = *(u32x2*)hv;
        if (s >= HALO) {
            const int row = s - HALO;
            #pragma unroll
            for (int q = 0; q < 4; ++q) {
                f32x2 e;
                e.x = fmaf(-2.f, rcpf(__expf(2.f * v[q]) + 1.f), 1.f);  // tanh
                e.y = __expf(-fabsf(v[q]));                             // e^-|x|
                tuS[(f4 * 4 + q) * 65 + row] = e;
            }
        }
    }
    __syncthreads();                                    // bar1

    // ---- proj via MFMA: wave -> 2 C-tiles (mt = wv>>1, nt = (wv&1)*2 + tb) ----
    const int mt = wv >> 1;
    const int marow = HALO + mt * 16 + (lane & 15);
    const int kcol  = (lane >> 4) * 8;
    f32x4 cfr[2] = {{0.f,0.f,0.f,0.f}, {0.f,0.f,0.f,0.f}};
    #pragma unroll
    for (int tb = 0; tb < 2; ++tb) {
        const int nt = (wv & 1) * 2 + tb;
        #pragma unroll
        for (int kt = 0; kt < 2; ++kt) {
            const f16x8 afr = *(const f16x8*)(&xsH[marow * XSTR + kt * 32 + kcol]);
            const f16x8 bfr = __builtin_bit_cast(f16x8, pwB[(nt * 2 + kt) * 64 + lane]);
            cfr[tb] = __builtin_amdgcn_mfma_f32_16x16x32_f16(afr, bfr, cfr[tb], 0, 0, 0);
        }
    }

    // ---- megaloop setup: lane = row r; wave's 8 feats ib..ib+7 (wave-uniform) ----
    const int r    = lane;
    const int ib_u = __builtin_amdgcn_readfirstlane(wv * 8);   // SGPR
    const float* wbase = wsm + ib_u;                           // uniform pointer
    f32x2 tiP[4], uiP[4];
    #pragma unroll
    for (int q = 0; q < 8; ++q) {
        const f32x2 e = tuS[(ib_u + q) * 65 + r];
        tiP[q >> 1][q & 1] = e.x;
        uiP[q >> 1][q & 1] = e.y;
    }

    float macc[8] = {0,0,0,0,0,0,0,0};
    f32x2 cac[4] = {{0,0},{0,0},{0,0},{0,0}};
    const f32x2 one2 = {1.f, 1.f};
    const int firrow = 8 * wv;

    // ---- megaloop m = 0..63: coupling all m (w via s_load); FIR for m < 58 ----
    #pragma unroll
    for (int m = 0; m < 64; ++m) {
        const f32x2 e = tuS[m * 65 + r];                 // b64, 2-way free
        const f32x4 wA = *(const f32x4*)(wbase + m * 64);     // uniform -> s_load
        const f32x4 wB = *(const f32x4*)(wbase + m * 64 + 4); // uniform -> s_load
        if (m < 58) {
            const float xv = __half2float(xsH[(firrow + m) * XSTR + lane]);
            #pragma unroll
            for (int r2 = 0; r2 < 8; ++r2)
                macc[r2] = fmaf(cpad2[r2 + 57 - m], xv, macc[r2]);  // SGPR coeff
        }
        const f32x2 tjj = {e.x, e.x}, ujj = {e.y, e.y};
        #pragma unroll
        for (int g = 0; g < 4; ++g) {
            const f32x2 d1  = __builtin_elementwise_fma(-tiP[g], tjj, one2);
            const f32x2 d2  = __builtin_elementwise_fma( uiP[g], ujj, one2);
            const f32x2 den = d1 * d2;
            f32x2 rr; rr.x = rcpf(den.x); rr.y = rcpf(den.y);
            const f32x2 s = (tiP[g] - tjj) * rr;
            f32x2 wg;
            wg.x = (g < 2) ? wA[2 * g] : wB[2 * (g - 2)];
            wg.y = (g < 2) ? wA[2 * g + 1] : wB[2 * (g - 2) + 1];
            cac[g] = __builtin_elementwise_fma(wg, s, cac[g]);   // pk_fma, SGPR-pair w
        }
    }

    // ---- memory-term store ----
    #pragma unroll
    for (int r2 = 0; r2 < 8; ++r2)
        memout[(size_t)(b * TT + t0 + firrow + r2) * 64 + lane] = macc[r2];

    __syncthreads();                                    // bar2 (tuS dead)

    // ---- proj C-frags -> P2 (overlays tuS) ----
    #pragma unroll
    for (int tb = 0; tb < 2; ++tb) {
        const int nt = (wv & 1) * 2 + tb;
        const int ic = nt * 16 + (lane & 15);
        const int rb = mt * 16 + (lane >> 4) * 4;
        #pragma unroll
        for (int reg = 0; reg < 4; ++reg)
            P2[ic * 65 + rb + reg] = cfr[tb][reg];
    }
    __syncthreads();                                    // bar3

    // ---- epilogue RMW: P2 <- 0.4c + 0.3(proj+pb)ksum ----
    const float kappa = kap[0];
    const float ksum  = (1.f - __expf(-kappa * (float)(t0 + r + 1))) *
                        rcpf(1.f - __expf(-kappa));
    #pragma unroll
    for (int q = 0; q < 8; ++q) {
        const float cv  = (q & 1) ? cac[q >> 1].y : cac[q >> 1].x;
        const int   idx = (ib_u + q) * 65 + r;
        P2[idx] = fmaf(0.4f, cv, 0.3f * (P2[idx] + pb[ib_u + q]) * ksum);
    }
    __syncthreads();                                    // bar4

    // ---- final store: wave rows 8wv..8wv+7, lane = feature (coalesced) ----
    #pragma unroll
    for (int rr2 = 0; rr2 < 8; ++rr2) {
        const int row = firrow + rr2;
        out[(size_t)(b * TT + t0 + row) * 64 + lane] =
            fmaf(0.3f, macc[rr2], P2[lane * 65 + row]);  // (lane+row)%32 distinct: free
    }
}

extern "C" void kernel_launch(void* const* d_in, const int* in_sizes, int n_in,
                              void* d_out, int out_size, void* d_ws, size_t ws_size,
                              hipStream_t stream) {
    const float* x   = (const float*)d_in[0];
    const float* W   = (const float*)d_in[1];
    const float* PW  = (const float*)d_in[2];
    const float* pb  = (const float*)d_in[3];
    const float* kap = (const float*)d_in[4];
    const float* cf  = (const float*)d_in[5];

    float* out    = (float*)d_out;
    float* memout = out + (size_t)4 * TT * FF;

    float*  wsmT  = (float*)d_ws;                        // 16 KB
    u32x4*  pwB   = (u32x4*)((char*)d_ws + 16384);       //  8 KB
    float*  cpad2 = (float*)((char*)d_ws + 24576);       // 260 B

    hipLaunchKernelGGL(prep_kernel, dim3(1), dim3(64, 4), 0, stream,
                       W, PW, cf, wsmT, pwB, cpad2);
    hipLaunchKernelGGL(mcao_main, dim3(4 * (TT / TILE)), dim3(512), 0, stream,
                       x, wsmT, pwB, cpad2, pb, kap, out, memout);
}